// Round 3
// baseline (353.475 us; speedup 1.0000x reference)
//
#include <hip/hip_runtime.h>

typedef unsigned short u16;
typedef unsigned int u32;
typedef __attribute__((ext_vector_type(8))) short short8;   // 8 x bf16
typedef __attribute__((ext_vector_type(4))) float f32x4;

// ---------------- workspace layout (bytes) ----------------
#define OFF_WM    0         // float[801]: wmean[0..799] (pad 0), [800]=mean(b_in)
#define OFF_WINF  3584      // u16 [25][8][64][8]  W_in B-fragment-linear   (204800 B)
#define OFF_WEGF  208384    // u16 [6][17][64][8]  experts+gate frag-linear (104448 B)
#define OFF_WCTXF 312832    // u16 [2][8][64][8]   W_ctx frag-linear        (16384 B)
#define OFF_WOUTF 329216    // u16 [4][64][8]      W_out frag-linear        (4096 B)

__device__ __forceinline__ u16 f2bf(float x) {
  union { float f; u32 u; } v; v.f = x;
  u32 r = v.u + 0x7FFFu + ((v.u >> 16) & 1u);   // RNE
  return (u16)(r >> 16);
}

// ------------------------------------------------------------------
// Prep: wmean for the exact fp32 t path; all weights -> bf16 in
// MFMA-B-fragment-linear order: frag[tile][lane][j] with
// k = kt*32 + (lane>>4)*8 + j, n = ct*16 + (lane&15).
// ------------------------------------------------------------------
__global__ void prep_kernel(const float* __restrict__ W_in, const float* __restrict__ b_in,
                            const float* __restrict__ W_gate, const float* __restrict__ W_exp,
                            const float* __restrict__ W_ctx, const float* __restrict__ W_out,
                            float* __restrict__ wm, u16* __restrict__ WinF,
                            u16* __restrict__ WegF, u16* __restrict__ WctxF,
                            u16* __restrict__ WoutF) {
  int idx = blockIdx.x * 256 + threadIdx.x;
  if (idx < 801) {
    if (idx == 800) {
      float s = 0.f;
      for (int j = 0; j < 128; ++j) s += b_in[j];
      wm[800] = s * (1.f / 128.f);
    } else if (idx >= 784) {
      wm[idx] = 0.f;
    } else {
      float s = 0.f;
      for (int j = 0; j < 128; ++j) s += W_in[idx * 128 + j];
      wm[idx] = s * (1.f / 128.f);
    }
  } else if (idx < 103201) {                    // WinF: 25*8 tiles
    int f = idx - 801;
    int j = f & 7, lane = (f >> 3) & 63, tile = f >> 9;
    int ct = tile & 7, kt = tile >> 3;
    int k = kt * 32 + ((lane >> 4) << 3) + j;
    int n = ct * 16 + (lane & 15);
    WinF[f] = (k < 784) ? f2bf(W_in[k * 128 + n]) : (u16)0;
  } else if (idx < 155425) {                    // WegF: 6*17 tiles
    int f = idx - 103201;
    int j = f & 7, lane = (f >> 3) & 63, tile = f >> 9;
    int kt = tile / 17, ct = tile - kt * 17;
    int k = kt * 32 + ((lane >> 4) << 3) + j;
    int n = ct * 16 + (lane & 15);
    float v = 0.f;
    if (n < 256) { int e = n >> 6, h = n & 63; v = W_exp[(e * 192 + k) * 64 + h]; }
    else if (n < 260) v = W_gate[k * 4 + (n - 256)];
    WegF[f] = f2bf(v);
  } else if (idx < 163617) {                    // WctxF: 2*8 tiles
    int f = idx - 155425;
    int j = f & 7, lane = (f >> 3) & 63, tile = f >> 9;
    int ct = tile & 7, kt = tile >> 3;
    int k = kt * 32 + ((lane >> 4) << 3) + j;
    int n = ct * 16 + (lane & 15);
    WctxF[f] = f2bf(W_ctx[k * 128 + n]);
  } else if (idx < 165665) {                    // WoutF: 4 tiles (N padded 3->16)
    int f = idx - 163617;
    int j = f & 7, lane = (f >> 3) & 63, kt = f >> 9;
    int k = kt * 32 + ((lane >> 4) << 3) + j;
    int n = lane & 15;
    WoutF[f] = (n < 3) ? f2bf(W_out[k * 3 + n]) : (u16)0;
  }
}

// ------------------------------------------------------------------
// Fused forward, barrier-free: 4 waves/WG, each wave owns 16 rows.
// Per-wave private LDS block (3840 u16 = 7680 B):
//   enh  [6][16][40]  (full block)            -- phase 1 -> phase 2
//   cmb  [2][16][40]  (aliases u16 [0,1280))  -- phase 2 -> phase 3
//   ctx  [16][136]    (aliases u16 [1280,3456)) -- phase 3 -> phase 4
// Aliasing is safe: same-wave DS ops are processed in order.
//
// Latency-focused revision (counters: all pipes <16% busy, occ 46%):
//  - phase 1: x/wm software-pipelined one kt ahead; all 8 B-frag loads
//    issued at iteration top so f2bf VALU work overlaps their latency.
//  - phase 2: gate + 4 experts merged into ONE kt loop over 17 column
//    tiles (17 independent loads+MFMAs per stage, 6 stages instead of
//    30), enh fragment read once per kt instead of 5x.
// ------------------------------------------------------------------
__global__ __launch_bounds__(256, 4)
void fused_kernel(const float* __restrict__ x,
                  const float* __restrict__ b_in, const float* __restrict__ b_gate,
                  const float* __restrict__ b_exp, const float* __restrict__ b_ctx,
                  const float* __restrict__ b_out,
                  const float* __restrict__ wm, const u16* __restrict__ WinF,
                  const u16* __restrict__ WegF, const u16* __restrict__ WctxF,
                  const u16* __restrict__ WoutF,
                  float* __restrict__ out) {
  __shared__ __align__(16) u16 smem[4 * 3840];
  const int tid = threadIdx.x;
  const int wv = tid >> 6;
  const int ln = tid & 63;
  const int cb = ln & 15;        // fragment col / A-row
  const int qr = ln >> 4;        // k-quad
  u16* enhW = smem + wv * 3840;
  u16* cmbW = enhW;
  u16* ctxW = enhW + 1280;

  const int grow = blockIdx.x * 64 + wv * 16;     // this wave's first row
  const float* xr = x + (size_t)(grow + cb) * 784;

  const f32x4 vz = {0.f, 0.f, 0.f, 0.f};
  const float4 z4 = make_float4(0.f, 0.f, 0.f, 0.f);

  // ---- Phase 1: projected = x @ W_in (MFMA) + exact fp32 t ----
  f32x4 acc[8];
  #pragma unroll
  for (int i = 0; i < 8; ++i) acc[i] = vz;
  float tp = 0.f;

  // prologue: load kt=0 operands (k0 = qr*8 <= 24, always in-bounds)
  float4 a0, a1, m0, m1;
  {
    const int k0 = qr * 8;
    a0 = *(const float4*)(xr + k0);
    a1 = *(const float4*)(xr + k0 + 4);
    m0 = *(const float4*)(wm + k0);
    m1 = *(const float4*)(wm + k0 + 4);
  }

  const u16* wbase = WinF + ln * 8;
  for (int kt = 0; kt < 25; ++kt) {
    // issue this kt's 8 B-fragment loads as early as possible
    const u16* wb = wbase + (size_t)kt * 4096;
    short8 Bf[8];
    #pragma unroll
    for (int ct = 0; ct < 8; ++ct)
      Bf[ct] = *(const short8*)(wb + ct * 512);

    // prefetch next kt's x / wm (zero at K-tail; WinF pad is also 0)
    float4 n0 = z4, n1 = z4, nm0 = z4, nm1 = z4;
    const int kn = kt * 32 + qr * 8 + 32;
    if (kt < 24 && kn < 784) {
      n0  = *(const float4*)(xr + kn);
      n1  = *(const float4*)(xr + kn + 4);
      nm0 = *(const float4*)(wm + kn);
      nm1 = *(const float4*)(wm + kn + 4);
    }

    // VALU work overlaps the in-flight loads
    tp += a0.x * m0.x + a0.y * m0.y + a0.z * m0.z + a0.w * m0.w
        + a1.x * m1.x + a1.y * m1.y + a1.z * m1.z + a1.w * m1.w;
    union { short8 s; u32 u[4]; } af;
    af.u[0] = (u32)f2bf(a0.x) | ((u32)f2bf(a0.y) << 16);
    af.u[1] = (u32)f2bf(a0.z) | ((u32)f2bf(a0.w) << 16);
    af.u[2] = (u32)f2bf(a1.x) | ((u32)f2bf(a1.y) << 16);
    af.u[3] = (u32)f2bf(a1.z) | ((u32)f2bf(a1.w) << 16);

    #pragma unroll
    for (int ct = 0; ct < 8; ++ct)
      acc[ct] = __builtin_amdgcn_mfma_f32_16x16x32_bf16(af.s, Bf[ct], acc[ct], 0, 0, 0);

    a0 = n0; a1 = n1; m0 = nm0; m1 = nm1;
  }

  // t: reduce partials across the 4 k-quads of row cb (all 4 copies get the sum)
  tp += __shfl_xor(tp, 16);
  tp += __shfl_xor(tp, 32);
  const float t = tp + wm[800];

  // enhanced[cols 0..127] = projected + b_in  (bf16, chunked [6][16][40])
  #pragma unroll
  for (int ct = 0; ct < 8; ++ct) {
    float bi = b_in[ct * 16 + cb];
    u16* dst = enhW + (ct >> 1) * 640 + (ct & 1) * 16 + cb;
    #pragma unroll
    for (int i = 0; i < 4; ++i)
      dst[(qr * 4 + i) * 40] = f2bf(acc[ct][i] + bi);
  }
  // enhanced[cols 128..191] = phasor bank. Lane (qr,cb): row cb, harmonics qr*8+1..qr*8+8
  {
    float phi = 7.f * t;
    float ss, cc, sd, cd;
    sincosf(phi * (float)(qr * 8 + 1), &ss, &cc);
    sincosf(phi, &sd, &cd);
    u16* pc = enhW + 4 * 640 + cb * 40 + qr * 8;
    u16* ps = enhW + 5 * 640 + cb * 40 + qr * 8;
    #pragma unroll
    for (int m = 0; m < 8; ++m) {
      pc[m] = f2bf(cc);
      ps[m] = f2bf(ss);
      float nc = cc * cd - ss * sd;
      ss = ss * cd + cc * sd;
      cc = nc;
    }
  }

  // ---- Phase 2: gate + 4 experts in ONE pass over K=192 (17 col tiles) ----
  // tiles 0..15 = experts (e*4+c2), tile 16 = gate (WegF layout already so)
  const u16* gbase = WegF + ln * 8;
  f32x4 ag[17];
  #pragma unroll
  for (int i = 0; i < 17; ++i) ag[i] = vz;
  for (int kt = 0; kt < 6; ++kt) {
    short8 Af = *(const short8*)(enhW + kt * 640 + cb * 40 + qr * 8);
    const u16* gb = gbase + (size_t)kt * 17 * 512;
    #pragma unroll
    for (int c = 0; c < 17; ++c) {
      short8 Bf = *(const short8*)(gb + c * 512);
      ag[c] = __builtin_amdgcn_mfma_f32_16x16x32_bf16(Af, Bf, ag[c], 0, 0, 0);
    }
  }

  // softmax over expert lanes cb=0..3 of each quad, then broadcast to all lanes
  float ge[4][4];                          // [expert][i]
  {
    float bg = b_gate[cb & 3];
    #pragma unroll
    for (int i = 0; i < 4; ++i) {
      float gi = ag[16][i] + bg;
      float mx = fmaxf(gi, __shfl_xor(gi, 1));
      mx = fmaxf(mx, __shfl_xor(mx, 2));
      float ev = __expf(gi - mx);
      float sv = ev + __shfl_xor(ev, 1);
      sv += __shfl_xor(sv, 2);
      float g = ev / sv;
      int base = qr * 16;
      ge[0][i] = __shfl(g, base + 0);
      ge[1][i] = __shfl(g, base + 1);
      ge[2][i] = __shfl(g, base + 2);
      ge[3][i] = __shfl(g, base + 3);
    }
  }

  // combined = sum_e gate_e * relu(expert_e)
  f32x4 cmb[4];
  #pragma unroll
  for (int i = 0; i < 4; ++i) cmb[i] = vz;
  #pragma unroll
  for (int e = 0; e < 4; ++e) {
    #pragma unroll
    for (int c2 = 0; c2 < 4; ++c2) {
      float be = b_exp[e * 64 + c2 * 16 + cb];
      #pragma unroll
      for (int i = 0; i < 4; ++i)
        cmb[c2][i] += ge[e][i] * fmaxf(ag[e * 4 + c2][i] + be, 0.f);
    }
  }
  // combined -> LDS (bf16, [2][16][40]); all phase-2 enh reads precede these writes
  #pragma unroll
  for (int c2 = 0; c2 < 4; ++c2) {
    u16* dst = cmbW + (c2 >> 1) * 640 + (c2 & 1) * 16 + cb;
    #pragma unroll
    for (int i = 0; i < 4; ++i)
      dst[(qr * 4 + i) * 40] = f2bf(cmb[c2][i]);
  }

  // ---- Phase 3: ctx = tanh(combined @ W_ctx + b_ctx), K=64 ----
  f32x4 acc3[8];
  #pragma unroll
  for (int i = 0; i < 8; ++i) acc3[i] = vz;
  #pragma unroll
  for (int kt = 0; kt < 2; ++kt) {
    short8 Af = *(const short8*)(cmbW + kt * 640 + cb * 40 + qr * 8);
    #pragma unroll
    for (int ct = 0; ct < 8; ++ct) {
      short8 Bf = *(const short8*)(WctxF + ((kt * 8 + ct) * 64 + ln) * 8);
      acc3[ct] = __builtin_amdgcn_mfma_f32_16x16x32_bf16(Af, Bf, acc3[ct], 0, 0, 0);
    }
  }
  #pragma unroll
  for (int ct = 0; ct < 8; ++ct) {
    float bc = b_ctx[ct * 16 + cb];
    u16* dst = ctxW + ct * 16 + cb;
    #pragma unroll
    for (int i = 0; i < 4; ++i) {
      float v = acc3[ct][i] + bc;
      float ex = __expf(2.f * v);            // tanh via exp; saturates correctly
      dst[(qr * 4 + i) * 136] = f2bf(1.f - 2.f / (ex + 1.f));
    }
  }

  // ---- Phase 4: logits = ctx @ W_out + b_out (MFMA, N padded to 16) ----
  f32x4 acc4 = vz;
  #pragma unroll
  for (int kt = 0; kt < 4; ++kt) {
    short8 Af = *(const short8*)(ctxW + cb * 136 + kt * 32 + qr * 8);
    short8 Bf = *(const short8*)(WoutF + (kt * 64 + ln) * 8);
    acc4 = __builtin_amdgcn_mfma_f32_16x16x32_bf16(Af, Bf, acc4, 0, 0, 0);
  }
  if (cb < 3) {
    float bo = b_out[cb];
    #pragma unroll
    for (int i = 0; i < 4; ++i)
      out[(size_t)(grow + qr * 4 + i) * 3 + cb] = acc4[i] + bo;
  }
}

extern "C" void kernel_launch(void* const* d_in, const int* in_sizes, int n_in,
                              void* d_out, int out_size, void* d_ws, size_t ws_size,
                              hipStream_t stream) {
  const float* x      = (const float*)d_in[0];
  const float* W_in   = (const float*)d_in[1];
  const float* b_in   = (const float*)d_in[2];
  const float* W_gate = (const float*)d_in[3];
  const float* b_gate = (const float*)d_in[4];
  const float* W_exp  = (const float*)d_in[5];
  const float* b_exp  = (const float*)d_in[6];
  const float* W_ctx  = (const float*)d_in[7];
  const float* b_ctx  = (const float*)d_in[8];
  const float* W_out  = (const float*)d_in[9];
  const float* b_out  = (const float*)d_in[10];
  float* out = (float*)d_out;

  char* ws = (char*)d_ws;
  float* wm  = (float*)(ws + OFF_WM);
  u16* WinF  = (u16*)(ws + OFF_WINF);
  u16* WegF  = (u16*)(ws + OFF_WEGF);
  u16* WctxF = (u16*)(ws + OFF_WCTXF);
  u16* WoutF = (u16*)(ws + OFF_WOUTF);

  const int B = in_sizes[0] / 784;
  prep_kernel<<<648, 256, 0, stream>>>(W_in, b_in, W_gate, W_exp, W_ctx, W_out,
                                       wm, WinF, WegF, WctxF, WoutF);
  fused_kernel<<<B / 64, 256, 0, stream>>>(x, b_in, b_gate, b_exp, b_ctx, b_out,
                                           wm, WinF, WegF, WctxF, WoutF, out);
}

// Round 4
// 339.481 us; speedup vs baseline: 1.0412x; 1.0412x over previous
//
#include <hip/hip_runtime.h>

typedef unsigned short u16;
typedef unsigned int u32;
typedef __attribute__((ext_vector_type(8))) short short8;   // 8 x bf16
typedef __attribute__((ext_vector_type(4))) float f32x4;

// ---------------- workspace layout (bytes) ----------------
#define OFF_WM    0         // float[801]: wmean[0..799] (pad 0), [800]=mean(b_in)
#define OFF_WINF  3584      // u16 [25][8][64][8]  W_in B-fragment-linear   (204800 B)
#define OFF_WEGF  208384    // u16 [6][17][64][8]  experts+gate frag-linear (104448 B)
#define OFF_WCTXF 312832    // u16 [2][8][64][8]   W_ctx frag-linear        (16384 B)
#define OFF_WOUTF 329216    // u16 [4][64][8]      W_out frag-linear        (4096 B)

__device__ __forceinline__ u16 f2bf(float x) {
  union { float f; u32 u; } v; v.f = x;
  u32 r = v.u + 0x7FFFu + ((v.u >> 16) & 1u);   // RNE
  return (u16)(r >> 16);
}

// ------------------------------------------------------------------
// Prep: wmean for the exact fp32 t path; all weights -> bf16 in
// MFMA-B-fragment-linear order: frag[tile][lane][j] with
// k = kt*32 + (lane>>4)*8 + j, n = ct*16 + (lane&15).
// ------------------------------------------------------------------
__global__ void prep_kernel(const float* __restrict__ W_in, const float* __restrict__ b_in,
                            const float* __restrict__ W_gate, const float* __restrict__ W_exp,
                            const float* __restrict__ W_ctx, const float* __restrict__ W_out,
                            float* __restrict__ wm, u16* __restrict__ WinF,
                            u16* __restrict__ WegF, u16* __restrict__ WctxF,
                            u16* __restrict__ WoutF) {
  int idx = blockIdx.x * 256 + threadIdx.x;
  if (idx < 801) {
    if (idx == 800) {
      float s = 0.f;
      for (int j = 0; j < 128; ++j) s += b_in[j];
      wm[800] = s * (1.f / 128.f);
    } else if (idx >= 784) {
      wm[idx] = 0.f;
    } else {
      float s = 0.f;
      for (int j = 0; j < 128; ++j) s += W_in[idx * 128 + j];
      wm[idx] = s * (1.f / 128.f);
    }
  } else if (idx < 103201) {                    // WinF: 25*8 tiles
    int f = idx - 801;
    int j = f & 7, lane = (f >> 3) & 63, tile = f >> 9;
    int ct = tile & 7, kt = tile >> 3;
    int k = kt * 32 + ((lane >> 4) << 3) + j;
    int n = ct * 16 + (lane & 15);
    WinF[f] = (k < 784) ? f2bf(W_in[k * 128 + n]) : (u16)0;
  } else if (idx < 155425) {                    // WegF: 6*17 tiles
    int f = idx - 103201;
    int j = f & 7, lane = (f >> 3) & 63, tile = f >> 9;
    int kt = tile / 17, ct = tile - kt * 17;
    int k = kt * 32 + ((lane >> 4) << 3) + j;
    int n = ct * 16 + (lane & 15);
    float v = 0.f;
    if (n < 256) { int e = n >> 6, h = n & 63; v = W_exp[(e * 192 + k) * 64 + h]; }
    else if (n < 260) v = W_gate[k * 4 + (n - 256)];
    WegF[f] = f2bf(v);
  } else if (idx < 163617) {                    // WctxF: 2*8 tiles
    int f = idx - 155425;
    int j = f & 7, lane = (f >> 3) & 63, tile = f >> 9;
    int ct = tile & 7, kt = tile >> 3;
    int k = kt * 32 + ((lane >> 4) << 3) + j;
    int n = ct * 16 + (lane & 15);
    WctxF[f] = f2bf(W_ctx[k * 128 + n]);
  } else if (idx < 165665) {                    // WoutF: 4 tiles (N padded 3->16)
    int f = idx - 163617;
    int j = f & 7, lane = (f >> 3) & 63, kt = f >> 9;
    int k = kt * 32 + ((lane >> 4) << 3) + j;
    int n = lane & 15;
    WoutF[f] = (n < 3) ? f2bf(W_out[k * 3 + n]) : (u16)0;
  }
}

// ------------------------------------------------------------------
// Fused forward, barrier-free: 4 waves/WG, each wave owns 32 rows
// (TWO 16-row MFMA groups) and loads every weight fragment ONCE for
// both groups. Rationale (round-3 counters): time is insensitive to
// HBM (131us at 22 GB/s cached pass) and to occupancy (46->42% no
// change) -> bound by per-CU L1/TCP request traffic, dominated by
// per-wave private weight-fragment streams. Doubling rows per wave
// halves weight bytes AND load instructions per output row.
//
// Per-wave private LDS: two groups x 3840 u16 (7680 B each):
//   enh  [6][16][40]  (full group block)      -- phase 1 -> phase 2
//   cmb  [2][16][40]  (aliases u16 [0,1280))  -- phase 2 -> phase 3
//   ctx  [16][136]    (aliases u16 [1280,3456)) -- phase 3 -> phase 4
// Aliasing is safe: same-wave DS ops are processed in order.
// ------------------------------------------------------------------
__global__ __launch_bounds__(256, 2)
void fused_kernel(const float* __restrict__ x,
                  const float* __restrict__ b_in, const float* __restrict__ b_gate,
                  const float* __restrict__ b_exp, const float* __restrict__ b_ctx,
                  const float* __restrict__ b_out,
                  const float* __restrict__ wm, const u16* __restrict__ WinF,
                  const u16* __restrict__ WegF, const u16* __restrict__ WctxF,
                  const u16* __restrict__ WoutF,
                  float* __restrict__ out) {
  __shared__ __align__(16) u16 smem[4 * 7680];
  const int tid = threadIdx.x;
  const int wv = tid >> 6;
  const int ln = tid & 63;
  const int cb = ln & 15;        // fragment col / A-row
  const int qr = ln >> 4;        // k-quad
  u16* enh0 = smem + wv * 7680;
  u16* enh1 = enh0 + 3840;
  u16* cmb0 = enh0;
  u16* cmb1 = enh1;
  u16* ctx0 = enh0 + 1280;
  u16* ctx1 = enh1 + 1280;

  const int grow = blockIdx.x * 128 + wv * 32;    // this wave's first row
  const float* xr0 = x + (size_t)(grow + cb) * 784;
  const float* xr1 = xr0 + (size_t)16 * 784;

  const f32x4 vz = {0.f, 0.f, 0.f, 0.f};

  // ---- Phase 1: projected = x @ W_in (MFMA) + exact fp32 t, 2 row-groups ----
  f32x4 acc0[8], acc1[8];
  #pragma unroll
  for (int i = 0; i < 8; ++i) { acc0[i] = vz; acc1[i] = vz; }
  float tp0 = 0.f, tp1 = 0.f;

  const u16* wbase = WinF + ln * 8;
  for (int kt = 0; kt < 25; ++kt) {
    // one weight-fragment stream serves BOTH row groups
    const u16* wb = wbase + (size_t)kt * 4096;
    short8 Bf[8];
    #pragma unroll
    for (int ct = 0; ct < 8; ++ct)
      Bf[ct] = *(const short8*)(wb + ct * 512);

    const int k0 = kt * 32 + qr * 8;
    float4 a0 = make_float4(0.f, 0.f, 0.f, 0.f), a1 = a0;
    float4 b0 = a0, b1 = a0, m0 = a0, m1 = a0;
    if (k0 < 784) {                       // K-tail: zero A (WinF pad also 0)
      a0 = *(const float4*)(xr0 + k0);
      a1 = *(const float4*)(xr0 + k0 + 4);
      b0 = *(const float4*)(xr1 + k0);
      b1 = *(const float4*)(xr1 + k0 + 4);
      m0 = *(const float4*)(wm + k0);
      m1 = *(const float4*)(wm + k0 + 4);
      tp0 += a0.x * m0.x + a0.y * m0.y + a0.z * m0.z + a0.w * m0.w
           + a1.x * m1.x + a1.y * m1.y + a1.z * m1.z + a1.w * m1.w;
      tp1 += b0.x * m0.x + b0.y * m0.y + b0.z * m0.z + b0.w * m0.w
           + b1.x * m1.x + b1.y * m1.y + b1.z * m1.z + b1.w * m1.w;
    }
    union { short8 s; u32 u[4]; } af, bf;
    af.u[0] = (u32)f2bf(a0.x) | ((u32)f2bf(a0.y) << 16);
    af.u[1] = (u32)f2bf(a0.z) | ((u32)f2bf(a0.w) << 16);
    af.u[2] = (u32)f2bf(a1.x) | ((u32)f2bf(a1.y) << 16);
    af.u[3] = (u32)f2bf(a1.z) | ((u32)f2bf(a1.w) << 16);
    bf.u[0] = (u32)f2bf(b0.x) | ((u32)f2bf(b0.y) << 16);
    bf.u[1] = (u32)f2bf(b0.z) | ((u32)f2bf(b0.w) << 16);
    bf.u[2] = (u32)f2bf(b1.x) | ((u32)f2bf(b1.y) << 16);
    bf.u[3] = (u32)f2bf(b1.z) | ((u32)f2bf(b1.w) << 16);

    #pragma unroll
    for (int ct = 0; ct < 8; ++ct) {
      acc0[ct] = __builtin_amdgcn_mfma_f32_16x16x32_bf16(af.s, Bf[ct], acc0[ct], 0, 0, 0);
      acc1[ct] = __builtin_amdgcn_mfma_f32_16x16x32_bf16(bf.s, Bf[ct], acc1[ct], 0, 0, 0);
    }
  }

  // t: reduce partials across the 4 k-quads of row cb
  tp0 += __shfl_xor(tp0, 16);
  tp0 += __shfl_xor(tp0, 32);
  tp1 += __shfl_xor(tp1, 16);
  tp1 += __shfl_xor(tp1, 32);
  const float mb = wm[800];
  const float t0 = tp0 + mb;
  const float t1 = tp1 + mb;

  // enhanced[cols 0..127] = projected + b_in  (bf16, chunked [6][16][40])
  #pragma unroll
  for (int ct = 0; ct < 8; ++ct) {
    float bi = b_in[ct * 16 + cb];
    u16* d0 = enh0 + (ct >> 1) * 640 + (ct & 1) * 16 + cb;
    u16* d1 = enh1 + (ct >> 1) * 640 + (ct & 1) * 16 + cb;
    #pragma unroll
    for (int i = 0; i < 4; ++i) {
      d0[(qr * 4 + i) * 40] = f2bf(acc0[ct][i] + bi);
      d1[(qr * 4 + i) * 40] = f2bf(acc1[ct][i] + bi);
    }
  }
  // enhanced[cols 128..191] = phasor bank, per group.
  #pragma unroll
  for (int g = 0; g < 2; ++g) {
    float t = g ? t1 : t0;
    u16* eW = g ? enh1 : enh0;
    float phi = 7.f * t;
    float ss, cc, sd, cd;
    sincosf(phi * (float)(qr * 8 + 1), &ss, &cc);
    sincosf(phi, &sd, &cd);
    u16* pc = eW + 4 * 640 + cb * 40 + qr * 8;
    u16* ps = eW + 5 * 640 + cb * 40 + qr * 8;
    #pragma unroll
    for (int m = 0; m < 8; ++m) {
      pc[m] = f2bf(cc);
      ps[m] = f2bf(ss);
      float nc = cc * cd - ss * sd;
      ss = ss * cd + cc * sd;
      cc = nc;
    }
  }

  // ---- Phase 2: gate pass (tile 16), then experts; B shared by both groups ----
  const u16* gbase = WegF + ln * 8;
  f32x4 g0 = vz, g1 = vz;
  #pragma unroll
  for (int kt = 0; kt < 6; ++kt) {
    short8 A0 = *(const short8*)(enh0 + kt * 640 + cb * 40 + qr * 8);
    short8 A1 = *(const short8*)(enh1 + kt * 640 + cb * 40 + qr * 8);
    short8 Bg = *(const short8*)(gbase + (size_t)(kt * 17 + 16) * 512);
    g0 = __builtin_amdgcn_mfma_f32_16x16x32_bf16(A0, Bg, g0, 0, 0, 0);
    g1 = __builtin_amdgcn_mfma_f32_16x16x32_bf16(A1, Bg, g1, 0, 0, 0);
  }

  // softmax over expert lanes cb=0..3 of each quad, broadcast to all lanes
  float ge0[4][4], ge1[4][4];              // [expert][i]
  {
    float bg = b_gate[cb & 3];
    #pragma unroll
    for (int i = 0; i < 4; ++i) {
      {
        float gi = g0[i] + bg;
        float mx = fmaxf(gi, __shfl_xor(gi, 1));
        mx = fmaxf(mx, __shfl_xor(mx, 2));
        float ev = __expf(gi - mx);
        float sv = ev + __shfl_xor(ev, 1);
        sv += __shfl_xor(sv, 2);
        float g = ev / sv;
        int base = qr * 16;
        ge0[0][i] = __shfl(g, base + 0);
        ge0[1][i] = __shfl(g, base + 1);
        ge0[2][i] = __shfl(g, base + 2);
        ge0[3][i] = __shfl(g, base + 3);
      }
      {
        float gi = g1[i] + bg;
        float mx = fmaxf(gi, __shfl_xor(gi, 1));
        mx = fmaxf(mx, __shfl_xor(mx, 2));
        float ev = __expf(gi - mx);
        float sv = ev + __shfl_xor(ev, 1);
        sv += __shfl_xor(sv, 2);
        float g = ev / sv;
        int base = qr * 16;
        ge1[0][i] = __shfl(g, base + 0);
        ge1[1][i] = __shfl(g, base + 1);
        ge1[2][i] = __shfl(g, base + 2);
        ge1[3][i] = __shfl(g, base + 3);
      }
    }
  }

  // experts one at a time (caps live AGPRs), combine incrementally
  f32x4 cA[4], cB[4];
  #pragma unroll
  for (int i = 0; i < 4; ++i) { cA[i] = vz; cB[i] = vz; }
  #pragma unroll
  for (int e = 0; e < 4; ++e) {
    f32x4 ae0[4], ae1[4];
    #pragma unroll
    for (int i = 0; i < 4; ++i) { ae0[i] = vz; ae1[i] = vz; }
    #pragma unroll
    for (int kt = 0; kt < 6; ++kt) {
      short8 A0 = *(const short8*)(enh0 + kt * 640 + cb * 40 + qr * 8);
      short8 A1 = *(const short8*)(enh1 + kt * 640 + cb * 40 + qr * 8);
      const u16* gb = gbase + (size_t)(kt * 17 + e * 4) * 512;
      #pragma unroll
      for (int c2 = 0; c2 < 4; ++c2) {
        short8 Bf = *(const short8*)(gb + c2 * 512);
        ae0[c2] = __builtin_amdgcn_mfma_f32_16x16x32_bf16(A0, Bf, ae0[c2], 0, 0, 0);
        ae1[c2] = __builtin_amdgcn_mfma_f32_16x16x32_bf16(A1, Bf, ae1[c2], 0, 0, 0);
      }
    }
    #pragma unroll
    for (int c2 = 0; c2 < 4; ++c2) {
      float be = b_exp[e * 64 + c2 * 16 + cb];
      #pragma unroll
      for (int i = 0; i < 4; ++i) {
        cA[c2][i] += ge0[e][i] * fmaxf(ae0[c2][i] + be, 0.f);
        cB[c2][i] += ge1[e][i] * fmaxf(ae1[c2][i] + be, 0.f);
      }
    }
  }
  // combined -> LDS (bf16, [2][16][40]); all phase-2 enh reads precede these writes
  #pragma unroll
  for (int c2 = 0; c2 < 4; ++c2) {
    u16* d0 = cmb0 + (c2 >> 1) * 640 + (c2 & 1) * 16 + cb;
    u16* d1 = cmb1 + (c2 >> 1) * 640 + (c2 & 1) * 16 + cb;
    #pragma unroll
    for (int i = 0; i < 4; ++i) {
      d0[(qr * 4 + i) * 40] = f2bf(cA[c2][i]);
      d1[(qr * 4 + i) * 40] = f2bf(cB[c2][i]);
    }
  }

  // ---- Phase 3: ctx = tanh(combined @ W_ctx + b_ctx), K=64 ----
  f32x4 c30[8], c31[8];
  #pragma unroll
  for (int i = 0; i < 8; ++i) { c30[i] = vz; c31[i] = vz; }
  #pragma unroll
  for (int kt = 0; kt < 2; ++kt) {
    short8 A0 = *(const short8*)(cmb0 + kt * 640 + cb * 40 + qr * 8);
    short8 A1 = *(const short8*)(cmb1 + kt * 640 + cb * 40 + qr * 8);
    #pragma unroll
    for (int ct = 0; ct < 8; ++ct) {
      short8 Bf = *(const short8*)(WctxF + ((kt * 8 + ct) * 64 + ln) * 8);
      c30[ct] = __builtin_amdgcn_mfma_f32_16x16x32_bf16(A0, Bf, c30[ct], 0, 0, 0);
      c31[ct] = __builtin_amdgcn_mfma_f32_16x16x32_bf16(A1, Bf, c31[ct], 0, 0, 0);
    }
  }
  #pragma unroll
  for (int ct = 0; ct < 8; ++ct) {
    float bc = b_ctx[ct * 16 + cb];
    u16* d0 = ctx0 + ct * 16 + cb;
    u16* d1 = ctx1 + ct * 16 + cb;
    #pragma unroll
    for (int i = 0; i < 4; ++i) {
      float v0 = c30[ct][i] + bc;
      float e0 = __expf(2.f * v0);           // tanh via exp; saturates correctly
      d0[(qr * 4 + i) * 136] = f2bf(1.f - 2.f / (e0 + 1.f));
      float v1 = c31[ct][i] + bc;
      float e1 = __expf(2.f * v1);
      d1[(qr * 4 + i) * 136] = f2bf(1.f - 2.f / (e1 + 1.f));
    }
  }

  // ---- Phase 4: logits = ctx @ W_out + b_out (MFMA, N padded to 16) ----
  f32x4 a40 = vz, a41 = vz;
  #pragma unroll
  for (int kt = 0; kt < 4; ++kt) {
    short8 A0 = *(const short8*)(ctx0 + cb * 136 + kt * 32 + qr * 8);
    short8 A1 = *(const short8*)(ctx1 + cb * 136 + kt * 32 + qr * 8);
    short8 Bf = *(const short8*)(WoutF + (kt * 64 + ln) * 8);
    a40 = __builtin_amdgcn_mfma_f32_16x16x32_bf16(A0, Bf, a40, 0, 0, 0);
    a41 = __builtin_amdgcn_mfma_f32_16x16x32_bf16(A1, Bf, a41, 0, 0, 0);
  }
  if (cb < 3) {
    float bo = b_out[cb];
    #pragma unroll
    for (int i = 0; i < 4; ++i) {
      out[(size_t)(grow + qr * 4 + i) * 3 + cb] = a40[i] + bo;
      out[(size_t)(grow + 16 + qr * 4 + i) * 3 + cb] = a41[i] + bo;
    }
  }
}

extern "C" void kernel_launch(void* const* d_in, const int* in_sizes, int n_in,
                              void* d_out, int out_size, void* d_ws, size_t ws_size,
                              hipStream_t stream) {
  const float* x      = (const float*)d_in[0];
  const float* W_in   = (const float*)d_in[1];
  const float* b_in   = (const float*)d_in[2];
  const float* W_gate = (const float*)d_in[3];
  const float* b_gate = (const float*)d_in[4];
  const float* W_exp  = (const float*)d_in[5];
  const float* b_exp  = (const float*)d_in[6];
  const float* W_ctx  = (const float*)d_in[7];
  const float* b_ctx  = (const float*)d_in[8];
  const float* W_out  = (const float*)d_in[9];
  const float* b_out  = (const float*)d_in[10];
  float* out = (float*)d_out;

  char* ws = (char*)d_ws;
  float* wm  = (float*)(ws + OFF_WM);
  u16* WinF  = (u16*)(ws + OFF_WINF);
  u16* WegF  = (u16*)(ws + OFF_WEGF);
  u16* WctxF = (u16*)(ws + OFF_WCTXF);
  u16* WoutF = (u16*)(ws + OFF_WOUTF);

  const int B = in_sizes[0] / 784;
  prep_kernel<<<648, 256, 0, stream>>>(W_in, b_in, W_gate, W_exp, W_ctx, W_out,
                                       wm, WinF, WegF, WctxF, WoutF);
  fused_kernel<<<B / 128, 256, 0, stream>>>(x, b_in, b_gate, b_exp, b_ctx, b_out,
                                            wm, WinF, WegF, WctxF, WoutF, out);
}